// Round 1
// baseline (596.043 us; speedup 1.0000x reference)
//
#include <hip/hip_runtime.h>

#define F_DIM 128

__device__ __forceinline__ void flush_acc(float* dst, const float4& a) {
    atomicAdd(dst + 0, a.x);
    atomicAdd(dst + 1, a.y);
    atomicAdd(dst + 2, a.z);
    atomicAdd(dst + 3, a.w);
}

// One 32-lane half-wave owns a contiguous chunk of rows. Lane j holds float4
// of features [4j..4j+3]. Dot via butterfly shuffle (width 32), sigmoid,
// register accumulation per segment, atomic flush on segment change.
__global__ __launch_bounds__(256) void fused_gate_segsum(
    const float* __restrict__ atom_feats, const float* __restrict__ vir_feats,
    const float* __restrict__ W_atom, const float* __restrict__ b_atom,
    const float* __restrict__ W_vir, const float* __restrict__ b_vir,
    const int* __restrict__ atom_seg, const int* __restrict__ vir_seg,
    float* __restrict__ out_atom, float* __restrict__ out_vir,
    float* __restrict__ logits,
    int n_atom, int n_vir, int g_atom, int rpg_atom, int rpg_vir)
{
    const int group = (int)((blockIdx.x * blockDim.x + threadIdx.x) >> 5);
    const int lane  = threadIdx.x & 31;

    const float* feats; const float* W; const float* bp; const int* seg;
    float* out; float* lg; long long n_rows; long long row_start; int rpg;
    if (group < g_atom) {
        feats = atom_feats; W = W_atom; bp = b_atom; seg = atom_seg;
        out = out_atom; lg = logits; n_rows = n_atom; rpg = rpg_atom;
        row_start = (long long)group * rpg;
    } else {
        const int g = group - g_atom;
        feats = vir_feats; W = W_vir; bp = b_vir; seg = vir_seg;
        out = out_vir; lg = nullptr; n_rows = n_vir; rpg = rpg_vir;
        row_start = (long long)g * rpg;
    }
    if (row_start >= n_rows) return;
    long long row_end = row_start + rpg;
    if (row_end > n_rows) row_end = n_rows;

    const float4 w4 = ((const float4*)W)[lane];
    const float bias = *bp;

    float4 acc = make_float4(0.f, 0.f, 0.f, 0.f);
    int cur = seg[row_start];
    float mylog = 0.f;   // logit of row (base + lane) within current 32-row window

    for (long long r = row_start; r < row_end; ++r) {
        const int s = seg[r];
        if (s != cur) {
            flush_acc(out + (size_t)cur * F_DIM + lane * 4, acc);
            acc = make_float4(0.f, 0.f, 0.f, 0.f);
            cur = s;
        }
        const float4 v = ((const float4*)(feats + (size_t)r * F_DIM))[lane];
        float dot = v.x * w4.x + v.y * w4.y + v.z * w4.z + v.w * w4.w;
        #pragma unroll
        for (int m = 16; m >= 1; m >>= 1) dot += __shfl_xor(dot, m, 32);
        const float logit = dot + bias;
        if (lg) {
            if (lane == (int)(r & 31)) mylog = logit;
            if ((r & 31) == 31) lg[r - 31 + lane] = mylog;   // coalesced 128B store
        }
        const float wgt = 1.0f / (1.0f + __expf(-logit));
        acc.x += wgt * v.x; acc.y += wgt * v.y;
        acc.z += wgt * v.z; acc.w += wgt * v.w;
    }
    flush_acc(out + (size_t)cur * F_DIM + lane * 4, acc);

    // logits tail (rows past the last aligned 32-window)
    if (lg) {
        const int rem = (int)(row_end & 31);
        if (rem && (row_start & ~31LL) <= (row_end & ~31LL) && lane < rem) {
            // only the final group of a non-multiple-of-32 n_rows hits this
            if ((row_end & ~31LL) >= row_start) lg[(row_end & ~31LL) + lane] = mylog;
        }
    }
}

extern "C" void kernel_launch(void* const* d_in, const int* in_sizes, int n_in,
                              void* d_out, int out_size, void* d_ws, size_t ws_size,
                              hipStream_t stream) {
    const float* atom_feats = (const float*)d_in[0];
    const float* vir_feats  = (const float*)d_in[1];
    const float* W_atom     = (const float*)d_in[2];
    const float* b_atom     = (const float*)d_in[3];
    const float* W_vir      = (const float*)d_in[4];
    const float* b_vir      = (const float*)d_in[5];
    const int*   atom_seg   = (const int*)d_in[6];
    const int*   vir_seg    = (const int*)d_in[7];

    const int n_atom = in_sizes[0] / F_DIM;
    const int n_vir  = in_sizes[1] / F_DIM;
    const int num_graphs = (out_size - n_atom) / (2 * F_DIM);

    float* out_atom = (float*)d_out;
    float* out_vir  = out_atom + (size_t)num_graphs * F_DIM;
    float* logits   = out_vir  + (size_t)num_graphs * F_DIM;

    // zero the two segment-sum regions (harness poisons d_out with 0xAA)
    hipMemsetAsync(d_out, 0, (size_t)2 * num_graphs * F_DIM * sizeof(float), stream);

    const int RPG_ATOM = 64;   // avg segment ~50 rows -> ~2 flushes/chunk
    const int RPG_VIR  = 16;   // avg segment ~4 rows  -> ~5 flushes/chunk
    const int g_atom = (n_atom + RPG_ATOM - 1) / RPG_ATOM;
    const int g_vir  = (n_vir  + RPG_VIR  - 1) / RPG_VIR;
    const int total_groups = g_atom + g_vir;
    const int block = 256;                      // 8 half-wave groups per block
    const int grid = (total_groups * 32 + block - 1) / block;

    fused_gate_segsum<<<grid, block, 0, stream>>>(
        atom_feats, vir_feats, W_atom, b_atom, W_vir, b_vir,
        atom_seg, vir_seg, out_atom, out_vir, logits,
        n_atom, n_vir, g_atom, RPG_ATOM, RPG_VIR);
}